// Round 12
// baseline (353.821 us; speedup 1.0000x reference)
//
#include <hip/hip_runtime.h>
#include <hip/hip_bf16.h>
#include <cstddef>

// BS=8, NE=128, ENT=768, REL=768, RANK=256, OUT=256
// M = 131072 rows; rel row-major [b][i][j][768]
// ws: l1 [1024*256 f32] | l2 [1024*256 f32] | W3g [196608 bf16 frag] | Weg [65536 bf16 frag]
// Fragment-major B panels: flat = ((kq*256 + n)*4 + g)*8 + e (kq=k/32, g=(k/8)%4, e=k%8)
//
// fused_main R12 — LDS-FREE, BARRIER-FREE GEMM1:
//   R3-R11 post-mortem: every rel-through-LDS variant (9 schedules) pinned at
//   fused 180-250us, MfmaUtil ~11%, vs ~85us floor. Invariant = LDS staging:
//   barrier lockstep/K-step + vmcnt FIFO coupling + LDS pipe load.
//   Fix: the verified A-fragment rel[fm*16+c16][kq*32+g*8+e] is 8 CONSECUTIVE
//   f32 per lane -> 2 contiguous dwordx4 straight from global; 4 g-groups x 16
//   rows tile full cachelines (100% utilization). Load to regs, cvt in-reg
//   (pk8, verified path), MFMA directly. Zero LDS, zero barriers, zero manual
//   waitcnt in the K-loop; 2-generation reg dbuf (~16KB HBM in flight/wave).
//   W3g frag-major direct from L2 (verbatim). acc layout identical to R8-R11
//   -> epilogue/GEMM2/LN/store verbatim (verified mapping preserved).

typedef __attribute__((ext_vector_type(8))) short short8;
typedef __attribute__((ext_vector_type(4))) float f32x4;

__device__ __forceinline__ unsigned short f2bf(float x) {
  union { float f; unsigned u; } v; v.f = x;
  unsigned r = (v.u + 0x7FFFu + ((v.u >> 16) & 1u)) >> 16;  // RNE
  return (unsigned short)r;
}
__device__ __forceinline__ unsigned short cvt1(float x) {
  return __bfloat16_as_ushort(__float2bfloat16(x));  // pairs to v_cvt_pk_bf16_f32
}
__device__ __forceinline__ f32x4 mfma16(short8 a, short8 b, f32x4 c) {
  return __builtin_amdgcn_mfma_f32_16x16x32_bf16(a, b, c, 0, 0, 0);
}
__device__ __forceinline__ short8 pk8(f32x4 x, f32x4 y) {
  short8 s;
  s[0] = (short)cvt1(x[0]); s[1] = (short)cvt1(x[1]);
  s[2] = (short)cvt1(x[2]); s[3] = (short)cvt1(x[3]);
  s[4] = (short)cvt1(y[0]); s[5] = (short)cvt1(y[1]);
  s[6] = (short)cvt1(y[2]); s[7] = (short)cvt1(y[3]);
  return s;
}

// ---------------- prep (grid 1280) -------------------------------------------
__global__ __launch_bounds__(256) void prep_all(
    const float* __restrict__ sub, const float* __restrict__ obj,
    const float* __restrict__ W1, const float* __restrict__ b1,
    const float* __restrict__ W2, const float* __restrict__ b2,
    const float* __restrict__ W3, const float* __restrict__ We,
    float* __restrict__ l1p, float* __restrict__ l2p,
    unsigned short* __restrict__ W3g, unsigned short* __restrict__ Weg) {
  const int tid = threadIdx.x;
  if (blockIdx.x >= 256) {
    int idx = (blockIdx.x - 256) * 256 + tid;
    if (idx < 196608) {
      int n = idx / 768, k = idx % 768;
      int f = ((k >> 5) * 256 + n) * 32 + ((k >> 3) & 3) * 8 + (k & 7);
      W3g[f] = f2bf(W3[idx]);
    }
    int j = idx - 196608;
    if (j >= 0 && j < 65536) {
      int n = j / 256, k = j % 256;
      int f = ((k >> 5) * 256 + n) * 32 + ((k >> 3) & 3) * 8 + (k & 7);
      Weg[f] = f2bf(We[j]);
    }
    return;
  }
  const int half = blockIdx.x >> 7;
  const float* x = half ? obj : sub;
  const float* W = half ? W2 : W1;
  const float* bias = half ? b2 : b1;
  float* outp = half ? l2p : l1p;

  __shared__ float xs[8][768];
  const int R0 = (blockIdx.x & 127) * 8;
  #pragma unroll
  for (int c = 0; c < 6; ++c) {
    int f4i = c * 256 + tid;
    int row = f4i / 192;
    int c4 = f4i % 192;
    *(float4*)&xs[row][c4 * 4] = *(const float4*)&x[(size_t)(R0 + row) * 768 + c4 * 4];
  }
  __syncthreads();
  const int col = tid;
  const float* Wr = W + (size_t)col * 768;
  float a[8] = {0.f, 0.f, 0.f, 0.f, 0.f, 0.f, 0.f, 0.f};
  for (int k4 = 0; k4 < 192; ++k4) {
    float4 wv = *(const float4*)&Wr[k4 * 4];
    #pragma unroll
    for (int r = 0; r < 8; ++r) {
      float4 xv = *(const float4*)&xs[r][k4 * 4];
      a[r] += wv.x * xv.x + wv.y * xv.y + wv.z * xv.z + wv.w * xv.w;
    }
  }
  float bb = bias[col];
  #pragma unroll
  for (int r = 0; r < 8; ++r)
    outp[(size_t)(R0 + r) * 256 + col] = a[r] + bb;
}

// ---------------- fused main -------------------------------------------------
__global__ __launch_bounds__(256, 2) void fused_main(
    const float* __restrict__ rel, const float* __restrict__ l1p,
    const float* __restrict__ l2p, const unsigned short* __restrict__ W3g,
    const unsigned short* __restrict__ Weg, const float* __restrict__ b3,
    const float* __restrict__ be, const float* __restrict__ lng,
    const float* __restrict__ lnb, float* __restrict__ out) {
  __shared__ unsigned short prod[64][256];  // 32 KB, XOR-swizzled (only LDS)
  __shared__ float ps[64][4], pq[64][4], mus[64], rss[64];

  const int tid = threadIdx.x;
  const int wave = tid >> 6, lane = tid & 63;
  const int g = lane >> 4, c16 = lane & 15;

  // XCD-bijective swizzle (2048 % 8 == 0)
  const int bid = (blockIdx.x & 7) * 256 + (blockIdx.x >> 3);
  const int R0 = bid * 64;
  const int b = R0 >> 14;
  const int rem = R0 & 16383;
  const int i = rem >> 7;
  const int j0 = rem & 127;  // 0 or 64

  const float* relBase = rel + (size_t)((b * 128 + i) * 128 + j0) * 768;

  // per-lane rel fragment pointers: row = fm*16 + c16, k-offset g*8
  const float* rp0 = relBase + (size_t)c16 * 768 + g * 8;
  // W3g frag-major: per-lane base for n = wave*64 + fn*16 + c16
  const unsigned short* bp = W3g + (size_t)(wave * 64 + c16) * 32 + g * 8;

  f32x4 acc1[4][4] = {};
  f32x4 ra[2][4][2];  // [gen][fm][half] rel f32 prefetch
  short8 Bw[2][4];    // [gen][fn] W3 fragments

#define LOADREL(G, KQ)                                                         \
  {                                                                            \
    _Pragma("unroll") for (int fm = 0; fm < 4; ++fm) {                         \
      const float* p_ = rp0 + fm * (16 * 768) + (KQ) * 32;                     \
      ra[G][fm][0] = *(const f32x4*)(p_);                                      \
      ra[G][fm][1] = *(const f32x4*)(p_ + 4);                                  \
    }                                                                          \
  }
#define LOADW(G, KQ)                                                           \
  {                                                                            \
    _Pragma("unroll") for (int fn = 0; fn < 4; ++fn)                           \
        Bw[G][fn] = *(const short8*)(bp + (size_t)(KQ) * 8192 + fn * 512);     \
  }

  // prologue: 2 generations in flight
  LOADREL(0, 0); LOADW(0, 0);
  LOADREL(1, 1); LOADW(1, 1);

  #pragma unroll
  for (int kq = 0; kq < 24; ++kq) {
    const int cur = kq & 1;
    // cvt rel(kq) to bf16 frags (compiler inserts counted vmcnt; ~2-iter window)
    short8 ah[4];
    #pragma unroll
    for (int fm = 0; fm < 4; ++fm) ah[fm] = pk8(ra[cur][fm][0], ra[cur][fm][1]);
    // MFMA tile kq (Bw[cur] latched at issue; safe to refill after)
    #pragma unroll
    for (int fn = 0; fn < 4; ++fn)
      #pragma unroll
      for (int fm = 0; fm < 4; ++fm)
        acc1[fm][fn] = mfma16(ah[fm], Bw[cur][fn], acc1[fm][fn]);
    // prefetch generation kq+2 into the buffers just consumed
    if (kq < 22) {
      LOADREL(cur, kq + 2);
      LOADW(cur, kq + 2);
    }
  }

  // ---- epilogue 1: prod = (l3 + b3) * l1 * l2 -> bf16 swizzled LDS ----
  const int colb = wave * 64 + c16;
  const float* l1row = l1p + (size_t)(b * 128 + i) * 256;
  float l1v[4], b3v[4];
  #pragma unroll
  for (int fn = 0; fn < 4; ++fn) {
    l1v[fn] = l1row[colb + fn * 16];
    b3v[fn] = b3[colb + fn * 16];
  }
  #pragma unroll
  for (int fm = 0; fm < 4; ++fm) {
    #pragma unroll
    for (int r = 0; r < 4; ++r) {
      const int m = fm * 16 + g * 4 + r;
      const float* l2row = l2p + (size_t)(b * 128 + j0 + m) * 256;
      #pragma unroll
      for (int fn = 0; fn < 4; ++fn) {
        float v = (acc1[fm][fn][r] + b3v[fn]) * l1v[fn] * l2row[colb + fn * 16];
        prod[m][(colb + fn * 16) ^ ((m & 7) << 3)] = f2bf(v);
      }
    }
  }
  __syncthreads();

  // ---- GEMM2: f = prod @ Web^T (Weg fragment-major) ----
  f32x4 acc2[4][4] = {};
  #pragma unroll
  for (int kk = 0; kk < 8; ++kk) {
    short8 a2[4];
    #pragma unroll
    for (int fm = 0; fm < 4; ++fm) {
      const int m = fm * 16 + c16;
      a2[fm] = *(const short8*)&prod[m][(kk * 32 + g * 8) ^ ((m & 7) << 3)];
    }
    #pragma unroll
    for (int fn = 0; fn < 4; ++fn) {
      const int n = wave * 64 + fn * 16 + c16;
      short8 bfr = *(const short8*)&Weg[(size_t)((kk * 256 + n) * 4 + g) * 8];
      #pragma unroll
      for (int fm = 0; fm < 4; ++fm)
        acc2[fm][fn] = mfma16(a2[fm], bfr, acc2[fm][fn]);
    }
  }

  // ---- LN stats: per-row sum/sumsq; 16-lane shfl reduce + cross-wave LDS ----
  float bev[4];
  #pragma unroll
  for (int fn = 0; fn < 4; ++fn) bev[fn] = be[colb + fn * 16];
  #pragma unroll
  for (int fm = 0; fm < 4; ++fm) {
    #pragma unroll
    for (int r = 0; r < 4; ++r) {
      float s1 = 0.f, s2 = 0.f;
      #pragma unroll
      for (int fn = 0; fn < 4; ++fn) {
        float v = acc2[fm][fn][r] + bev[fn];
        s1 += v; s2 += v * v;
      }
      #pragma unroll
      for (int off = 1; off < 16; off <<= 1) {
        s1 += __shfl_xor(s1, off);
        s2 += __shfl_xor(s2, off);
      }
      if (c16 == 0) {
        const int m = fm * 16 + g * 4 + r;
        ps[m][wave] = s1; pq[m][wave] = s2;
      }
    }
  }
  __syncthreads();
  if (tid < 64) {
    float s = ps[tid][0] + ps[tid][1] + ps[tid][2] + ps[tid][3];
    float q = pq[tid][0] + pq[tid][1] + pq[tid][2] + pq[tid][3];
    float mu = s * 0.00390625f;
    float var = q * 0.00390625f - mu * mu;
    mus[tid] = mu;
    rss[tid] = rsqrtf(var + 1e-6f);
  }
  __syncthreads();

  // ---- store: (f - mu)*rs*g + b ----
  float gv[4], bhv[4];
  #pragma unroll
  for (int fn = 0; fn < 4; ++fn) {
    gv[fn] = lng[colb + fn * 16];
    bhv[fn] = lnb[colb + fn * 16];
  }
  #pragma unroll
  for (int fm = 0; fm < 4; ++fm) {
    #pragma unroll
    for (int r = 0; r < 4; ++r) {
      const int m = fm * 16 + g * 4 + r;
      const float mu = mus[m], rs = rss[m];
      float* orow = out + (size_t)(R0 + m) * 256;
      #pragma unroll
      for (int fn = 0; fn < 4; ++fn) {
        float v = acc2[fm][fn][r] + bev[fn];
        orow[colb + fn * 16] = (v - mu) * rs * gv[fn] + bhv[fn];
      }
    }
  }
#undef LOADREL
#undef LOADW
}

extern "C" void kernel_launch(void* const* d_in, const int* in_sizes, int n_in,
                              void* d_out, int out_size, void* d_ws, size_t ws_size,
                              hipStream_t stream) {
  const float* sub = (const float*)d_in[0];
  const float* obj = (const float*)d_in[1];
  const float* rel = (const float*)d_in[2];
  const float* W1 = (const float*)d_in[3];
  const float* b1 = (const float*)d_in[4];
  const float* W2 = (const float*)d_in[5];
  const float* b2 = (const float*)d_in[6];
  const float* W3 = (const float*)d_in[7];
  const float* b3 = (const float*)d_in[8];
  const float* We = (const float*)d_in[9];
  const float* be = (const float*)d_in[10];
  const float* lng = (const float*)d_in[11];
  const float* lnb = (const float*)d_in[12];
  float* out = (float*)d_out;

  float* ws = (float*)d_ws;
  float* l1p = ws;
  float* l2p = ws + 262144;
  unsigned short* W3g = (unsigned short*)(ws + 524288);
  unsigned short* Weg = W3g + 196608;

  prep_all<<<1280, 256, 0, stream>>>(sub, obj, W1, b1, W2, b2, W3, We, l1p, l2p, W3g, Weg);
  fused_main<<<2048, 256, 0, stream>>>(rel, l1p, l2p, W3g, Weg, b3, be, lng, lnb, out);
}